// Round 5
// baseline (501.915 us; speedup 1.0000x reference)
//
#include <hip/hip_runtime.h>

typedef __bf16 bf16x8 __attribute__((ext_vector_type(8)));
typedef float  f32x4  __attribute__((ext_vector_type(4)));

#define NPIX   65536
#define CCH    64
#define KCODE  1024
#define HW     4096
#define Q_ELEMS 4194304
#define LOSS0_OFF 4194304
#define LOSS1_OFF 4194305
#define IDX_OFF   4194306
#define WINDOW 1.0e-4f

// ws layout (bytes)
#define WS_EBP  0        // 262144: E as bf16 hi/lo MFMA-B fragments [64 tiles][2 kstep][2 split][64 lane][16B]
#define WS_SE1  262144   // 4096: 1.0f + np.sum(e*e)  (phase-B shifted norm, positive scores)
#define WS_SEX  266240   // 4096: np.sum(e*e) exact np order (fix kernel)
#define WS_IDX  270336   // 262144: chosen code per pixel (int)
#define WS_CNT  532480   // 4: flagged count
#define WS_LIST 532544   // 262144: flagged pixel list

// numpy pairwise_sum middle branch for n=64 on squares (bit-exact np.sum(x*x))
template <typename F>
__device__ __forceinline__ float np_pairwise64_sq(F v) {
    float r[8];
#pragma unroll
    for (int j = 0; j < 8; ++j) r[j] = __fmul_rn(v(j), v(j));
#pragma unroll
    for (int i = 8; i < 64; i += 8) {
#pragma unroll
        for (int j = 0; j < 8; ++j)
            r[j] = __fadd_rn(r[j], __fmul_rn(v(i + j), v(i + j)));
    }
    return __fadd_rn(
        __fadd_rn(__fadd_rn(r[0], r[1]), __fadd_rn(r[2], r[3])),
        __fadd_rn(__fadd_rn(r[4], r[5]), __fadd_rn(r[6], r[7])));
}

// ---- prep: pack E into bf16 hi/lo B-fragments, norms, zero accumulators ----
__global__ void prep_kernel(const float* __restrict__ emb, char* __restrict__ ws,
                            float* __restrict__ out) {
    const int tid = blockIdx.x * 256 + threadIdx.x;     // 0..17407
    if (tid < 16384) {
        const int lane = tid & 63, rest = tid >> 6;
        const int h = rest & 1, s = (rest >> 1) & 1, t = rest >> 2;  // t=tile 0..63
        const int n = lane & 15, q = lane >> 4;
        // B[k][n] fragment: lane(q,n) holds k=q*8+j (kstep s), value E[t*16+n][s*32+q*8+j]
        const float* src = emb + (size_t)(t * 16 + n) * CCH + s * 32 + q * 8;
        bf16x8 f;
#pragma unroll
        for (int j = 0; j < 8; ++j) {
            float v = src[j];
            __bf16 hi = (__bf16)v;
            f[j] = (h == 0) ? hi : (__bf16)__fsub_rn(v, (float)hi);
        }
        *(bf16x8*)(ws + WS_EBP + (size_t)tid * 16) = f;
    } else if (tid < 16384 + KCODE) {
        const int k = tid - 16384;
        const float* e = emb + (size_t)k * CCH;
        float se = np_pairwise64_sq([&](int i) { return e[i]; });
        ((float*)(ws + WS_SEX))[k] = se;
        ((float*)(ws + WS_SE1))[k] = __fadd_rn(1.0f, se);
    }
    if (tid == 0) {
        *(int*)(ws + WS_CNT) = 0;
        out[LOSS0_OFF] = 0.f;
        out[LOSS1_OFF] = 0.f;
    }
}

// ---- phase B: approx scores via bf16x2 MFMA, top-2 + ambiguity flag ----
__launch_bounds__(256)
__global__ void vqb_kernel(const float* __restrict__ z, char* __restrict__ ws) {
    __shared__ __align__(16) char lds[32768];           // union: z-transpose, then B dbuf
    const int t = threadIdx.x;
    const int lane = t & 63;
    const int w = t >> 6;
    const int n = lane & 15, q = lane >> 4;
    const int pix0 = blockIdx.x * 64;                   // 64 pixels/block, 16/wave
    const int b = pix0 >> 12;
    const int hwb = (pix0 & 4095) + w * 16;

    const float4* ebp4 = (const float4*)(ws + WS_EBP);
    const float* se1   = (const float*)(ws + WS_SE1);
    int* idxws = (int*)(ws + WS_IDX);
    int* cnt   = (int*)(ws + WS_CNT);
    int* list  = (int*)(ws + WS_LIST);

    // prologue: lane=channel loads 16 pixels; transpose via LDS; build A frags
    const float4* zrow = (const float4*)(z + (size_t)(b * CCH + lane) * HW + hwb);
    float4 zl0 = zrow[0], zl1 = zrow[1], zl2 = zrow[2], zl3 = zrow[3];

    float4 stg[4];                                      // prefetch staging chunk 0
#pragma unroll
    for (int r = 0; r < 4; ++r) stg[r] = ebp4[r * 256 + t];

    float* ztf = (float*)lds;                           // [4 waves][64 c][16 p]
    float4* ztw = (float4*)(ztf + (w * 64 + lane) * 16);
    ztw[0] = zl0; ztw[1] = zl1; ztw[2] = zl2; ztw[3] = zl3;
    __builtin_amdgcn_s_waitcnt(0);                      // wave-local LDS RAW

    bf16x8 Ah0, Ah1, Al0, Al1;                          // A[m=n][k=q*8+j], kstep 0/1
#pragma unroll
    for (int j = 0; j < 8; ++j) {
        float v0 = ztf[(w * 64 + q * 8 + j) * 16 + n];
        float v1 = ztf[(w * 64 + 32 + q * 8 + j) * 16 + n];
        __bf16 h0 = (__bf16)v0, h1 = (__bf16)v1;
        Ah0[j] = h0; Al0[j] = (__bf16)__fsub_rn(v0, (float)h0);
        Ah1[j] = h1; Al1[j] = (__bf16)__fsub_rn(v1, (float)h1);
    }
    __syncthreads();                                    // zt reads done; buffers free

    float b0d[4], b1d[4]; int b0k[4];
#pragma unroll
    for (int e = 0; e < 4; ++e) { b0d[e] = 3.0e38f; b1d[e] = 3.0e38f; b0k[e] = 0; }

    for (int ch = 0; ch < 16; ++ch) {                   // 16 chunks x 64 codes
        char* cur = lds + ((ch & 1) << 14);             // no pointer array (addrspace)
        float4* bw = (float4*)cur;
#pragma unroll
        for (int r = 0; r < 4; ++r) bw[r * 256 + t] = stg[r];
        __syncthreads();
        if (ch < 15) {
#pragma unroll
            for (int r = 0; r < 4; ++r) stg[r] = ebp4[(size_t)(ch + 1) * 1024 + r * 256 + t];
        }
        const char* bb = cur;
#pragma unroll
        for (int tt = 0; tt < 4; ++tt) {                // 4 code-tiles of 16
            bf16x8 Bh0 = *(const bf16x8*)(bb + ((tt * 4 + 0) * 64 + lane) * 16);
            bf16x8 Bl0 = *(const bf16x8*)(bb + ((tt * 4 + 1) * 64 + lane) * 16);
            bf16x8 Bh1 = *(const bf16x8*)(bb + ((tt * 4 + 2) * 64 + lane) * 16);
            bf16x8 Bl1 = *(const bf16x8*)(bb + ((tt * 4 + 3) * 64 + lane) * 16);
            const int kk = ch * 64 + tt * 16 + n;
            const float se1v = se1[kk];
            f32x4 acc = {0.f, 0.f, 0.f, 0.f};
            acc = __builtin_amdgcn_mfma_f32_16x16x32_bf16(Ah0, Bh0, acc, 0, 0, 0);
            acc = __builtin_amdgcn_mfma_f32_16x16x32_bf16(Ah1, Bh1, acc, 0, 0, 0);
            acc = __builtin_amdgcn_mfma_f32_16x16x32_bf16(Ah0, Bl0, acc, 0, 0, 0);
            acc = __builtin_amdgcn_mfma_f32_16x16x32_bf16(Ah1, Bl1, acc, 0, 0, 0);
            acc = __builtin_amdgcn_mfma_f32_16x16x32_bf16(Al0, Bh0, acc, 0, 0, 0);
            acc = __builtin_amdgcn_mfma_f32_16x16x32_bf16(Al1, Bh1, acc, 0, 0, 0);
#pragma unroll
            for (int e = 0; e < 4; ++e) {               // C row=(lane>>4)*4+e, col=n
                float d = __builtin_fmaf(-2.0f, acc[e], se1v);   // 1+se-2dot > 0
                bool c0 = d < b0d[e];
                bool c1 = d < b1d[e];
                b1d[e] = c0 ? b0d[e] : (c1 ? d : b1d[e]);
                b0d[e] = c0 ? d : b0d[e];
                b0k[e] = c0 ? kk : b0k[e];
            }
        }
    }

    // merge top-2 across the 16 col-lanes of each quad group
#pragma unroll
    for (int m = 1; m < 16; m <<= 1) {
#pragma unroll
        for (int e = 0; e < 4; ++e) {
            float od = __shfl_xor(b0d[e], m, 16);
            int   ok = __shfl_xor(b0k[e], m, 16);
            float o1 = __shfl_xor(b1d[e], m, 16);
            float hi = fmaxf(b0d[e], od);
            b1d[e] = fminf(fminf(b1d[e], o1), hi);
            bool take = (od < b0d[e]) || (od == b0d[e] && ok < b0k[e]);
            b0d[e] = take ? od : b0d[e];
            b0k[e] = take ? ok : b0k[e];
        }
    }
#pragma unroll
    for (int e = 0; e < 4; ++e) {
        if (n == e) {                                   // one writer per row q*4+e
            int pixel = pix0 + w * 16 + q * 4 + e;
            idxws[pixel] = b0k[e];
            if (__fsub_rn(b1d[e], b0d[e]) <= WINDOW) {  // ambiguous -> exact rescan
                int pos = atomicAdd(cnt, 1);
                list[pos] = pixel;
            }
        }
    }
}

// ---- fix: bit-exact reference rescore (all 1024 codes) for flagged pixels ----
__launch_bounds__(256)
__global__ void fix_kernel(const float* __restrict__ z, const float* __restrict__ emb,
                           char* __restrict__ ws) {
    const int w = threadIdx.x >> 6, lane = threadIdx.x & 63;
    const int gw = blockIdx.x * 4 + w;                  // 256 waves total
    const int total = *(const int*)(ws + WS_CNT);
    const int* list = (const int*)(ws + WS_LIST);
    const float* sex = (const float*)(ws + WS_SEX);
    int* idxws = (int*)(ws + WS_IDX);
    __shared__ float zsh[4][64];

    for (int i = gw; i < total; i += 256) {
        const int pixel = list[i];
        const int b = pixel >> 12, hw = pixel & 4095;
        zsh[w][lane] = z[(size_t)(b * CCH + lane) * HW + hw];
        __builtin_amdgcn_s_waitcnt(0);                  // wave-local broadcast ready
        float zv[64];
#pragma unroll
        for (int c = 0; c < 64; ++c) zv[c] = zsh[w][c];
        const float szz = np_pairwise64_sq([&](int i2) { return zv[i2]; });
        unsigned long long best = ~0ULL;
        for (int it = 0; it < 16; ++it) {
            const int k = it * 64 + lane;
            const float* ek = emb + (size_t)k * CCH;
            float dot = 0.f;
#pragma unroll
            for (int c = 0; c < 64; ++c) dot = __builtin_fmaf(zv[c], ek[c], dot);
            // exact reference: fl(fl(szz+se) - 2*dot), d>0 -> u64 bit order; low=k ties
            float d = __fsub_rn(__fadd_rn(szz, sex[k]), __fadd_rn(dot, dot));
            unsigned long long cand =
                ((unsigned long long)__float_as_uint(d) << 32) | (unsigned)k;
            best = cand < best ? cand : best;
        }
#pragma unroll
        for (int m = 1; m < 64; m <<= 1) {
            unsigned long long o = __shfl_xor(best, m, 64);
            best = o < best ? o : best;
        }
        if (lane == 0) idxws[pixel] = (int)(unsigned)best;
    }
}

// ---- epilogue: gather + STE q-write + idx + losses (bit-exact as R2/R3) ----
__launch_bounds__(256)
__global__ void epi_kernel(const float* __restrict__ z, const float* __restrict__ emb,
                           const char* __restrict__ ws, float* __restrict__ out) {
    const int t = threadIdx.x;
    const int p = blockIdx.x * 128 + (t & 127);         // 128 pixels/block, 2 thr each
    const int half = t >> 7;
    const int b = p >> 12, hw = p & 4095;
    const int k = ((const int*)(ws + WS_IDX))[p];
    const float* ek = emb + (size_t)k * CCH + half * 32;
    float lsum = 0.f;
#pragma unroll 8
    for (int c = 0; c < 32; ++c) {
        const int cc = half * 32 + c;
        float zc = z[(size_t)(b * CCH + cc) * HW + hw];
        float diff = __fsub_rn(ek[c], zc);
        out[(size_t)(b * CCH + cc) * HW + hw] = __fadd_rn(zc, diff);
        lsum = __builtin_fmaf(diff, diff, lsum);
    }
    if (half == 0) out[IDX_OFF + p] = (float)k;
#pragma unroll
    for (int off = 32; off > 0; off >>= 1) lsum += __shfl_down(lsum, off, 64);
    __shared__ float red[4];
    if ((t & 63) == 0) red[t >> 6] = lsum;
    __syncthreads();
    if (t == 0) {
        float v = (red[0] + red[1] + red[2] + red[3]) * (1.0f / (float)Q_ELEMS);
        atomicAdd(out + LOSS0_OFF, v);
        atomicAdd(out + LOSS1_OFF, v);
    }
}

extern "C" void kernel_launch(void* const* d_in, const int* in_sizes, int n_in,
                              void* d_out, int out_size, void* d_ws, size_t ws_size,
                              hipStream_t stream) {
    const float* z   = (const float*)d_in[0];
    const float* emb = (const float*)d_in[1];
    float* out = (float*)d_out;
    char* ws = (char*)d_ws;

    prep_kernel<<<dim3(68),   dim3(256), 0, stream>>>(emb, ws, out);
    vqb_kernel <<<dim3(1024), dim3(256), 0, stream>>>(z, ws);
    fix_kernel <<<dim3(64),   dim3(256), 0, stream>>>(z, emb, ws);
    epi_kernel <<<dim3(512),  dim3(256), 0, stream>>>(z, emb, ws, out);
}

// Round 6
// 218.968 us; speedup vs baseline: 2.2922x; 2.2922x over previous
//
#include <hip/hip_runtime.h>

typedef __bf16 bf16x8 __attribute__((ext_vector_type(8)));
typedef float  f32x4  __attribute__((ext_vector_type(4)));

#define NPIX   65536
#define CCH    64
#define KCODE  1024
#define HW     4096
#define Q_ELEMS 4194304
#define LOSS0_OFF 4194304
#define LOSS1_OFF 4194305
#define IDX_OFF   4194306
#define WINDOW 1.0e-4f

// ws layout (bytes)
#define WS_EBP  0        // 262144: E as bf16 hi/lo MFMA-B fragments
#define WS_SE1  262144   // 4096: 1.0f + np.sum(e*e)
#define WS_SEX  266240   // 4096: np.sum(e*e) exact np order
#define WS_IDX  270336   // 262144: chosen code per pixel (int)
#define WS_CNT  532480   // 4: flagged count
#define WS_LIST 532544   // 262144: flagged pixel list

// numpy pairwise_sum middle branch for n=64 on squares (bit-exact np.sum(x*x))
template <typename F>
__device__ __forceinline__ float np_pairwise64_sq(F v) {
    float r[8];
#pragma unroll
    for (int j = 0; j < 8; ++j) r[j] = __fmul_rn(v(j), v(j));
#pragma unroll
    for (int i = 8; i < 64; i += 8) {
#pragma unroll
        for (int j = 0; j < 8; ++j)
            r[j] = __fadd_rn(r[j], __fmul_rn(v(i + j), v(i + j)));
    }
    return __fadd_rn(
        __fadd_rn(__fadd_rn(r[0], r[1]), __fadd_rn(r[2], r[3])),
        __fadd_rn(__fadd_rn(r[4], r[5]), __fadd_rn(r[6], r[7])));
}

// ---- prep: pack E into bf16 hi/lo B-fragments, norms, zero accumulators ----
__global__ void prep_kernel(const float* __restrict__ emb, char* __restrict__ ws,
                            float* __restrict__ out) {
    const int tid = blockIdx.x * 256 + threadIdx.x;     // 0..17407
    if (tid < 16384) {
        const int lane = tid & 63, rest = tid >> 6;
        const int h = rest & 1, s = (rest >> 1) & 1, t = rest >> 2;  // t=tile 0..63
        const int n = lane & 15, q = lane >> 4;
        const float* src = emb + (size_t)(t * 16 + n) * CCH + s * 32 + q * 8;
        bf16x8 f;
#pragma unroll
        for (int j = 0; j < 8; ++j) {
            float v = src[j];
            __bf16 hi = (__bf16)v;
            f[j] = (h == 0) ? hi : (__bf16)__fsub_rn(v, (float)hi);
        }
        *(bf16x8*)(ws + WS_EBP + (size_t)tid * 16) = f;
    } else if (tid < 16384 + KCODE) {
        const int k = tid - 16384;
        const float* e = emb + (size_t)k * CCH;
        float se = np_pairwise64_sq([&](int i) { return e[i]; });
        ((float*)(ws + WS_SEX))[k] = se;
        ((float*)(ws + WS_SE1))[k] = __fadd_rn(1.0f, se);
    }
    if (tid == 0) {
        *(int*)(ws + WS_CNT) = 0;
        out[LOSS0_OFF] = 0.f;
        out[LOSS1_OFF] = 0.f;
    }
}

// ---- phase B: approx scores via bf16x2 MFMA, top-2 + ambiguity flag ----
__launch_bounds__(256)
__global__ void vqb_kernel(const float* __restrict__ z, char* __restrict__ ws) {
    __shared__ __align__(16) char lds[32768];
    const int t = threadIdx.x;
    const int lane = t & 63;
    const int w = t >> 6;
    const int n = lane & 15, q = lane >> 4;
    const int pix0 = blockIdx.x * 64;
    const int b = pix0 >> 12;
    const int hwb = (pix0 & 4095) + w * 16;

    const float4* ebp4 = (const float4*)(ws + WS_EBP);
    const float* se1   = (const float*)(ws + WS_SE1);
    int* idxws = (int*)(ws + WS_IDX);
    int* cnt   = (int*)(ws + WS_CNT);
    int* list  = (int*)(ws + WS_LIST);

    const float4* zrow = (const float4*)(z + (size_t)(b * CCH + lane) * HW + hwb);
    float4 zl0 = zrow[0], zl1 = zrow[1], zl2 = zrow[2], zl3 = zrow[3];

    float4 stg[4];
#pragma unroll
    for (int r = 0; r < 4; ++r) stg[r] = ebp4[r * 256 + t];

    float* ztf = (float*)lds;                           // [4 waves][64 c][16 p]
    float4* ztw = (float4*)(ztf + (w * 64 + lane) * 16);
    ztw[0] = zl0; ztw[1] = zl1; ztw[2] = zl2; ztw[3] = zl3;
    __builtin_amdgcn_s_waitcnt(0);

    bf16x8 Ah0, Ah1, Al0, Al1;
#pragma unroll
    for (int j = 0; j < 8; ++j) {
        float v0 = ztf[(w * 64 + q * 8 + j) * 16 + n];
        float v1 = ztf[(w * 64 + 32 + q * 8 + j) * 16 + n];
        __bf16 h0 = (__bf16)v0, h1 = (__bf16)v1;
        Ah0[j] = h0; Al0[j] = (__bf16)__fsub_rn(v0, (float)h0);
        Ah1[j] = h1; Al1[j] = (__bf16)__fsub_rn(v1, (float)h1);
    }
    __syncthreads();

    float b0d[4], b1d[4]; int b0k[4];
#pragma unroll
    for (int e = 0; e < 4; ++e) { b0d[e] = 3.0e38f; b1d[e] = 3.0e38f; b0k[e] = 0; }

    for (int ch = 0; ch < 16; ++ch) {
        char* cur = lds + ((ch & 1) << 14);
        float4* bw = (float4*)cur;
#pragma unroll
        for (int r = 0; r < 4; ++r) bw[r * 256 + t] = stg[r];
        __syncthreads();
        if (ch < 15) {
#pragma unroll
            for (int r = 0; r < 4; ++r) stg[r] = ebp4[(size_t)(ch + 1) * 1024 + r * 256 + t];
        }
        const char* bb = cur;
#pragma unroll
        for (int tt = 0; tt < 4; ++tt) {
            bf16x8 Bh0 = *(const bf16x8*)(bb + ((tt * 4 + 0) * 64 + lane) * 16);
            bf16x8 Bl0 = *(const bf16x8*)(bb + ((tt * 4 + 1) * 64 + lane) * 16);
            bf16x8 Bh1 = *(const bf16x8*)(bb + ((tt * 4 + 2) * 64 + lane) * 16);
            bf16x8 Bl1 = *(const bf16x8*)(bb + ((tt * 4 + 3) * 64 + lane) * 16);
            const int kk = ch * 64 + tt * 16 + n;
            const float se1v = se1[kk];
            f32x4 acc = {0.f, 0.f, 0.f, 0.f};
            acc = __builtin_amdgcn_mfma_f32_16x16x32_bf16(Ah0, Bh0, acc, 0, 0, 0);
            acc = __builtin_amdgcn_mfma_f32_16x16x32_bf16(Ah1, Bh1, acc, 0, 0, 0);
            acc = __builtin_amdgcn_mfma_f32_16x16x32_bf16(Ah0, Bl0, acc, 0, 0, 0);
            acc = __builtin_amdgcn_mfma_f32_16x16x32_bf16(Ah1, Bl1, acc, 0, 0, 0);
            acc = __builtin_amdgcn_mfma_f32_16x16x32_bf16(Al0, Bh0, acc, 0, 0, 0);
            acc = __builtin_amdgcn_mfma_f32_16x16x32_bf16(Al1, Bh1, acc, 0, 0, 0);
#pragma unroll
            for (int e = 0; e < 4; ++e) {
                float d = __builtin_fmaf(-2.0f, acc[e], se1v);
                bool c0 = d < b0d[e];
                bool c1 = d < b1d[e];
                b1d[e] = c0 ? b0d[e] : (c1 ? d : b1d[e]);
                b0d[e] = c0 ? d : b0d[e];
                b0k[e] = c0 ? kk : b0k[e];
            }
        }
    }

#pragma unroll
    for (int m = 1; m < 16; m <<= 1) {
#pragma unroll
        for (int e = 0; e < 4; ++e) {
            float od = __shfl_xor(b0d[e], m, 16);
            int   ok = __shfl_xor(b0k[e], m, 16);
            float o1 = __shfl_xor(b1d[e], m, 16);
            float hi = fmaxf(b0d[e], od);
            b1d[e] = fminf(fminf(b1d[e], o1), hi);
            bool take = (od < b0d[e]) || (od == b0d[e] && ok < b0k[e]);
            b0d[e] = take ? od : b0d[e];
            b0k[e] = take ? ok : b0k[e];
        }
    }
#pragma unroll
    for (int e = 0; e < 4; ++e) {
        if (n == e) {
            int pixel = pix0 + w * 16 + q * 4 + e;
            idxws[pixel] = b0k[e];
            if (__fsub_rn(b1d[e], b0d[e]) <= WINDOW) {
                int pos = atomicAdd(cnt, 1);
                list[pos] = pixel;
            }
        }
    }
}

// ---- fix v2: exact rescore of flagged pixels, LDS-tiled codebook ----
// 256 blocks x 256 thr; 16 pixels/block-iter; wave w -> pixels 4w..4w+3.
__launch_bounds__(256)
__global__ void fix_kernel(const float* __restrict__ z, const float* __restrict__ emb,
                           char* __restrict__ ws) {
    __shared__ __align__(16) float lt[64 * 68];     // lt[k][c], row stride 68 (16B-mult)
    __shared__ __align__(16) float zsh[16 * 68];    // zsh[p][c], row stride 68
    __shared__ float szz_sh[16];
    const int t = threadIdx.x, lane = t & 63, w = t >> 6;
    const int total = *(const int*)(ws + WS_CNT);
    const int* list = (const int*)(ws + WS_LIST);
    const float* sex = (const float*)(ws + WS_SEX);
    int* idxws = (int*)(ws + WS_IDX);

    for (int base = blockIdx.x * 16; base < total; base += 256 * 16) {
        const int npix = min(16, total - base);
        {   // stage z for up to 16 pixels: thread t -> pixel t>>4, channels (t&15)+16j
            const int p = t >> 4, cq = t & 15;
            if (p < npix) {
                const int pixel = list[base + p];
                const int b = pixel >> 12, hw = pixel & 4095;
#pragma unroll
                for (int j = 0; j < 4; ++j) {
                    const int c = cq + j * 16;
                    zsh[p * 68 + c] = z[(size_t)(b * CCH + c) * HW + hw];
                }
            }
        }
        __syncthreads();
        if (t < npix)
            szz_sh[t] = np_pairwise64_sq([&](int i) { return zsh[t * 68 + i]; });
        __syncthreads();

        unsigned long long best[4];
#pragma unroll
        for (int e = 0; e < 4; ++e) best[e] = ~0ULL;
        const int p0 = w * 4;

        for (int ch = 0; ch < 16; ++ch) {
            {   // stage 64-code chunk: coalesced float4 global -> b128 LDS
                const int r = t >> 2, qq = t & 3;
                const float4* src = (const float4*)(emb + (size_t)(ch * 64 + r) * CCH + qq * 16);
                float4* dst = (float4*)(lt + r * 68 + qq * 16);
#pragma unroll
                for (int j4 = 0; j4 < 4; ++j4) dst[j4] = src[j4];
            }
            __syncthreads();
            const int k = ch * 64 + lane;
            const float sk = sex[k];
            float a0 = 0.f, a1 = 0.f, a2 = 0.f, a3 = 0.f;
#pragma unroll
            for (int cq = 0; cq < 16; ++cq) {
                const float4 ev = *(const float4*)(lt + lane * 68 + cq * 4);  // code row
                const float4 z0 = *(const float4*)(zsh + (p0 + 0) * 68 + cq * 4);
                const float4 z1 = *(const float4*)(zsh + (p0 + 1) * 68 + cq * 4);
                const float4 z2 = *(const float4*)(zsh + (p0 + 2) * 68 + cq * 4);
                const float4 z3 = *(const float4*)(zsh + (p0 + 3) * 68 + cq * 4);
                // ascending-c sequential fmaf chain == reference BLAS sdot order
                a0 = __builtin_fmaf(z0.x, ev.x, a0); a0 = __builtin_fmaf(z0.y, ev.y, a0);
                a0 = __builtin_fmaf(z0.z, ev.z, a0); a0 = __builtin_fmaf(z0.w, ev.w, a0);
                a1 = __builtin_fmaf(z1.x, ev.x, a1); a1 = __builtin_fmaf(z1.y, ev.y, a1);
                a1 = __builtin_fmaf(z1.z, ev.z, a1); a1 = __builtin_fmaf(z1.w, ev.w, a1);
                a2 = __builtin_fmaf(z2.x, ev.x, a2); a2 = __builtin_fmaf(z2.y, ev.y, a2);
                a2 = __builtin_fmaf(z2.z, ev.z, a2); a2 = __builtin_fmaf(z2.w, ev.w, a2);
                a3 = __builtin_fmaf(z3.x, ev.x, a3); a3 = __builtin_fmaf(z3.y, ev.y, a3);
                a3 = __builtin_fmaf(z3.z, ev.z, a3); a3 = __builtin_fmaf(z3.w, ev.w, a3);
            }
            float dd[4];
            dd[0] = __fsub_rn(__fadd_rn(szz_sh[p0 + 0], sk), __fadd_rn(a0, a0));
            dd[1] = __fsub_rn(__fadd_rn(szz_sh[p0 + 1], sk), __fadd_rn(a1, a1));
            dd[2] = __fsub_rn(__fadd_rn(szz_sh[p0 + 2], sk), __fadd_rn(a2, a2));
            dd[3] = __fsub_rn(__fadd_rn(szz_sh[p0 + 3], sk), __fadd_rn(a3, a3));
#pragma unroll
            for (int e = 0; e < 4; ++e) {
                unsigned long long cand =
                    ((unsigned long long)__float_as_uint(dd[e]) << 32) | (unsigned)k;
                best[e] = cand < best[e] ? cand : best[e];
            }
            __syncthreads();   // lt reuse next chunk
        }

#pragma unroll
        for (int e = 0; e < 4; ++e) {
#pragma unroll
            for (int m = 1; m < 64; m <<= 1) {
                unsigned long long o = __shfl_xor(best[e], m, 64);
                best[e] = o < best[e] ? o : best[e];
            }
            if (lane == 0 && p0 + e < npix)
                idxws[list[base + p0 + e]] = (int)(unsigned)best[e];
        }
    }
}

// ---- epilogue: gather + STE q-write + idx + losses (bit-exact as R2/R3) ----
__launch_bounds__(256)
__global__ void epi_kernel(const float* __restrict__ z, const float* __restrict__ emb,
                           const char* __restrict__ ws, float* __restrict__ out) {
    const int t = threadIdx.x;
    const int p = blockIdx.x * 128 + (t & 127);
    const int half = t >> 7;
    const int b = p >> 12, hw = p & 4095;
    const int k = ((const int*)(ws + WS_IDX))[p];
    const float* ek = emb + (size_t)k * CCH + half * 32;
    float lsum = 0.f;
#pragma unroll 8
    for (int c = 0; c < 32; ++c) {
        const int cc = half * 32 + c;
        float zc = z[(size_t)(b * CCH + cc) * HW + hw];
        float diff = __fsub_rn(ek[c], zc);
        out[(size_t)(b * CCH + cc) * HW + hw] = __fadd_rn(zc, diff);
        lsum = __builtin_fmaf(diff, diff, lsum);
    }
    if (half == 0) out[IDX_OFF + p] = (float)k;
#pragma unroll
    for (int off = 32; off > 0; off >>= 1) lsum += __shfl_down(lsum, off, 64);
    __shared__ float red[4];
    if ((t & 63) == 0) red[t >> 6] = lsum;
    __syncthreads();
    if (t == 0) {
        float v = (red[0] + red[1] + red[2] + red[3]) * (1.0f / (float)Q_ELEMS);
        atomicAdd(out + LOSS0_OFF, v);
        atomicAdd(out + LOSS1_OFF, v);
    }
}

extern "C" void kernel_launch(void* const* d_in, const int* in_sizes, int n_in,
                              void* d_out, int out_size, void* d_ws, size_t ws_size,
                              hipStream_t stream) {
    const float* z   = (const float*)d_in[0];
    const float* emb = (const float*)d_in[1];
    float* out = (float*)d_out;
    char* ws = (char*)d_ws;

    prep_kernel<<<dim3(68),   dim3(256), 0, stream>>>(emb, ws, out);
    vqb_kernel <<<dim3(1024), dim3(256), 0, stream>>>(z, ws);
    fix_kernel <<<dim3(256),  dim3(256), 0, stream>>>(z, emb, ws);
    epi_kernel <<<dim3(512),  dim3(256), 0, stream>>>(z, emb, ws, out);
}